// Round 3
// baseline (508.698 us; speedup 1.0000x reference)
//
#include <hip/hip_runtime.h>

// y = x @ (weight * blockscale)^T ; x[8192,4096] f32, weight[4096,4096] f32,
// w_scale[32,32] f32, out f32 [8192,4096].
#define M_DIM 8192
#define K_DIM 4096
#define O_DIM 4096
#define QB    128
#define BK    64     // K per tile
#define BMT   256    // 256x256 output tile, 8 waves (2M x 4N)
#define BNT   256

typedef __attribute__((ext_vector_type(8))) short  short8;   // 8 bf16
typedef __attribute__((ext_vector_type(4))) float  floatx4;  // MFMA acc

#define AS1 __attribute__((address_space(1)))
#define AS3 __attribute__((address_space(3)))

// fp32 -> bf16 bits, round-to-nearest-even
__device__ __forceinline__ short f2bf(float f) {
    unsigned u = __float_as_uint(f);
    unsigned r = u + 0x7fffu + ((u >> 16) & 1u);
    return (short)(r >> 16);
}

// ---- pre-pass, split into two branch-free grid-stride kernels (G11) ----
// Residual-time analysis: cvt_fused ran ~229us (1.3 TB/s for 302 MB) in all
// rounds, just below the top-5 counter cutoff. Structural suspects: the
// two-region branch and the 12288-block one-shot grid. This rewrite removes
// both; if unchanged, it surfaces as the top dispatch with counters.
__global__ __launch_bounds__(256) void cvt_x(const float* __restrict__ x,
                                             short* __restrict__ xb) {
    const size_t N8 = (size_t)M_DIM * K_DIM / 8;
    const size_t stride = (size_t)gridDim.x * 256;
    for (size_t t = (size_t)blockIdx.x * 256 + threadIdx.x; t < N8; t += stride) {
        size_t i = t * 8;
        floatx4 f0 = *(const floatx4*)(x + i);
        floatx4 f1 = *(const floatx4*)(x + i + 4);
        short8 o;
        o[0] = f2bf(f0[0]); o[1] = f2bf(f0[1]); o[2] = f2bf(f0[2]); o[3] = f2bf(f0[3]);
        o[4] = f2bf(f1[0]); o[5] = f2bf(f1[1]); o[6] = f2bf(f1[2]); o[7] = f2bf(f1[3]);
        *(short8*)(xb + i) = o;
    }
}

__global__ __launch_bounds__(256) void cvt_w(const float* __restrict__ w,
                                             const float* __restrict__ s,
                                             short* __restrict__ wb) {
    const size_t N8 = (size_t)O_DIM * K_DIM / 8;
    const size_t stride = (size_t)gridDim.x * 256;
    for (size_t t = (size_t)blockIdx.x * 256 + threadIdx.x; t < N8; t += stride) {
        size_t i = t * 8;
        int o = (int)(i >> 12);            // / K_DIM
        int k = (int)(i & (K_DIM - 1));
        float sc = s[(o >> 7) * (K_DIM / QB) + (k >> 7)];
        floatx4 f0 = *(const floatx4*)(w + i);
        floatx4 f1 = *(const floatx4*)(w + i + 4);
        short8 v;
        v[0] = f2bf(f0[0] * sc); v[1] = f2bf(f0[1] * sc);
        v[2] = f2bf(f0[2] * sc); v[3] = f2bf(f0[3] * sc);
        v[4] = f2bf(f1[0] * sc); v[5] = f2bf(f1[1] * sc);
        v[6] = f2bf(f1[2] * sc); v[7] = f2bf(f1[3] * sc);
        *(short8*)(wb + i) = v;
    }
}

// ---- 256x256 8-phase bf16 GEMM: read-ahead + deep-prefetch stage map ----
// Iter = tiles T (buf0) + T+1 (buf1), 8 phases. Stage slots (1 half-tile ea):
//   p0,p1: A(T+1)h0,h1 -> buf1     p4,p5: A(T+2)h0,h1 -> buf0
//   p2,p3: B(T+2)h0,h1 -> buf0     p6,p7: B(T+3)h0,h1 -> buf1
// vmcnt(4) at p3 and p7 only. Steady state at p3: queue = [B(T+1)(4 leftover),
// A(T+1)(4), B(T+2)(4)] -> confirm B(T+1)+A(T+1), leave B(T+2) in flight.
// Latency cover: B h1 = 4 phases, A h1 = 2, A h0 = 3 (round-2 gave B only 1
// phase; with A/B thrashing L2 per-XCD -> L3/HBM latency 600-2000cy, each p3
// confirm stalled the whole barrier-locked block; FETCH 297MB vs 96 ideal).
// Race-freedom: every LDS region's reads complete (per-wave counted lgkm +
// closing barrier) >=1 phase before its restage issues; every stage confirmed
// by vmcnt+barrier before first read:
//   lsA[c]: a1(T) read p0, confirmed p2-lgkm0 -> restage A(T+2) at p4,p5 OK
//   lsB[c]: b1(T) read p0, confirmed p1-lgkm8 -> restage B(T+2) at p2,p3 OK
//   lsB[n]: b1(T+1) read p4, confirmed p5-lgkm8 -> restage B(T+3) at p6,p7 OK
//   lsA[n]: a1(T+1) read p4, confirmed p6-lgkm0 -> restage A(T+3) next p0 OK
// Read-ahead: a0,b0 of the next tile issue at p3/p7 after the vmcnt+barrier.
#define WLG12 asm volatile("s_waitcnt lgkmcnt(12)" ::: "memory")
#define WLG8  asm volatile("s_waitcnt lgkmcnt(8)" ::: "memory")
#define WLG0  asm volatile("s_waitcnt lgkmcnt(0)" ::: "memory")
#define WVM4  asm volatile("s_waitcnt vmcnt(4)" ::: "memory")
#define WVM0  asm volatile("s_waitcnt vmcnt(0)" ::: "memory")
#define BARR  __builtin_amdgcn_s_barrier()
#define SCHEDB __builtin_amdgcn_sched_barrier(0)
#define SP1   __builtin_amdgcn_s_setprio(1)
#define SP0   __builtin_amdgcn_s_setprio(0)

#define LDA4(DST, BUF, ROFF)                                                    \
    _Pragma("unroll")                                                           \
    for (int mi = 0; mi < 4; ++mi) {                                            \
        DST[mi][0] = *(const short8*)&lsA[BUF][rA + (ROFF) + mi * 1024 + pc0];  \
        DST[mi][1] = *(const short8*)&lsA[BUF][rA + (ROFF) + mi * 1024 + pc1];  \
    }

#define LDB2(DST, BUF, ROFF)                                                    \
    _Pragma("unroll")                                                           \
    for (int ni = 0; ni < 2; ++ni) {                                            \
        DST[ni][0] = *(const short8*)&lsB[BUF][rB + (ROFF) + ni * 1024 + pc0];  \
        DST[ni][1] = *(const short8*)&lsB[BUF][rB + (ROFF) + ni * 1024 + pc1];  \
    }

#define RDA0(B) LDA4(a0, B, 0)
#define RDA1(B) LDA4(a1, B, 4096)
#define RDB0(B) LDB2(b0, B, 0)
#define RDB1(B) LDB2(b1, B, 2048)

#define MM16(AF, BF, MO, NO)                                                    \
    _Pragma("unroll")                                                           \
    for (int mi = 0; mi < 4; ++mi)                                              \
        _Pragma("unroll")                                                       \
        for (int ni = 0; ni < 2; ++ni)                                          \
            _Pragma("unroll")                                                   \
            for (int ks = 0; ks < 2; ++ks)                                      \
                acc[(MO) + mi][(NO) + ni] = __builtin_amdgcn_mfma_f32_16x16x32_bf16( \
                    AF[mi][ks], BF[ni][ks], acc[(MO) + mi][(NO) + ni], 0, 0, 0);

#define STAGE(LS, BUF, GP, KOFF, H)                                             \
    __builtin_amdgcn_global_load_lds(                                           \
        (const AS1 void*)((GP) + (size_t)((H) * 128) * K_DIM + (KOFF)),         \
        (AS3 void*)&LS[BUF][(H) * 128 * BK + dst], 16, 0, 0);                   \
    __builtin_amdgcn_global_load_lds(                                           \
        (const AS1 void*)((GP) + (size_t)((H) * 128 + 64) * K_DIM + (KOFF)),    \
        (AS3 void*)&LS[BUF][((H) * 128 + 64) * BK + dst], 16, 0, 0);

// MFMA cluster wrapper
#define MF(WAIT, Q) BARR; WAIT; SCHEDB; SP1; Q SP0; BARR; SCHEDB;

__global__ __launch_bounds__(512, 2) void gemm_bt(const short* __restrict__ A,
                                                  const short* __restrict__ B,
                                                  float* __restrict__ C) {
    __shared__ __align__(16) short lsA[2][BMT * BK];   // 64 KiB
    __shared__ __align__(16) short lsB[2][BNT * BK];   // 64 KiB

    const int tid  = threadIdx.x;
    const int lane = tid & 63;
    const int wave = tid >> 6;
    const int wr   = wave >> 2;     // 0..1
    const int wc   = wave & 3;      // 0..3

    // bijective XCD map: 512 blocks, 64 per XCD; XCD x owns bn stripe
    // {2x, 2x+1} (4 MiB of B resident in its L2); consecutive j alternate bn.
    const int id  = blockIdx.x;
    const int xcd = id & 7;
    const int j   = id >> 3;
    const int bm  = j >> 1;                  // 0..31
    const int bn  = (xcd << 1) | (j & 1);    // 0..15

    // staging: thread covers row sr=tid>>3 (+64 per second load), phys chunk
    // tid&7; logical chunk = (tid&7)^(sr&7), invariant under row+64/+128.
    const int sr  = tid >> 3;
    const int csw = ((tid & 7) ^ (sr & 7)) << 3;
    const int dst = tid * 8;                 // = sr*64 + (tid&7)*8
    const short* gA = A + (size_t)(bm * BMT + sr) * K_DIM + csw;
    const short* gB = B + (size_t)(bn * BNT + sr) * K_DIM + csw;

    // fragment reads (chunk-XOR swizzle matches staging)
    const int frow = lane & 15;
    const int fc   = lane >> 4;
    const int fsw  = frow & 7;
    const int pc0  = (fc ^ fsw) << 3;        // ks=0 physical chunk * 8
    const int pc1  = ((4 + fc) ^ fsw) << 3;  // ks=1
    const int rA   = (wr * 128 + frow) * BK;
    const int rB   = (wc * 64 + frow) * BK;

    floatx4 acc[8][4];
#pragma unroll
    for (int mi = 0; mi < 8; ++mi)
#pragma unroll
        for (int ni = 0; ni < 4; ++ni)
            acc[mi][ni] = (floatx4){0.f, 0.f, 0.f, 0.f};

    short8 a0[4][2], a1[4][2], b0[2][2], b1[2][2];

    // prologue: A0,B0 -> buf0, B1 -> buf1 (12 loads); vmcnt(4) confirms A0,B0,
    // leaves B1 in flight (= steady-state leftover); read-ahead tile0 a0,b0.
    STAGE(lsA, 0, gA, 0, 0)
    STAGE(lsA, 0, gA, 0, 1)
    STAGE(lsB, 0, gB, 0, 0)
    STAGE(lsB, 0, gB, 0, 1)
    STAGE(lsB, 1, gB, 64, 0)
    STAGE(lsB, 1, gB, 64, 1)
    WVM4; BARR; SCHEDB;
    RDA0(0); RDB0(0);

#pragma unroll 1
    for (int it = 0; it < 31; ++it) {
        // ---- tile T (buf0) ----
        // p0
        RDB1(0); RDA1(0);
        STAGE(lsA, 1, gA, 64, 0)
        MF(WLG12, MM16(a0, b0, 0, 0))
        // p1
        STAGE(lsA, 1, gA, 64, 1)
        MF(WLG8,  MM16(a0, b1, 0, 2))
        // p2
        STAGE(lsB, 0, gB, 128, 0)
        MF(WLG0,  MM16(a1, b0, 4, 0))
        // p3: confirm B(T+1)+A(T+1); read-ahead tile T+1 a0,b0
        STAGE(lsB, 0, gB, 128, 1)
        WVM4; BARR; SCHEDB;
        RDA0(1); RDB0(1);
        WLG12; SCHEDB; SP1; MM16(a1, b1, 4, 2) SP0; BARR; SCHEDB;

        // ---- tile T+1 (buf1) ----
        // p4
        RDB1(1); RDA1(1);
        STAGE(lsA, 0, gA, 128, 0)
        MF(WLG12, MM16(a0, b0, 0, 0))
        // p5
        STAGE(lsA, 0, gA, 128, 1)
        MF(WLG8,  MM16(a0, b1, 0, 2))
        // p6
        STAGE(lsB, 1, gB, 192, 0)
        MF(WLG0,  MM16(a1, b0, 4, 0))
        // p7: confirm B(T+2)+A(T+2); read-ahead tile T+2 a0,b0
        STAGE(lsB, 1, gB, 192, 1)
        WVM4; BARR; SCHEDB;
        RDA0(0); RDB0(0);
        WLG12; SCHEDB; SP1; MM16(a1, b1, 4, 2) SP0; BARR; SCHEDB;

        gA += 128;
        gB += 128;
    }

    // ---- peeled tiles 62 (buf0) + 63 (buf1); only A(63) left to stage ----
    RDB1(0); RDA1(0);
    STAGE(lsA, 1, gA, 64, 0)
    MF(WLG12, MM16(a0, b0, 0, 0))
    STAGE(lsA, 1, gA, 64, 1)
    MF(WLG8,  MM16(a0, b1, 0, 2))
    MF(WLG0,  MM16(a1, b0, 4, 0))
    WVM0; BARR; SCHEDB;
    RDA0(1); RDB0(1);
    WLG12; SCHEDB; SP1; MM16(a1, b1, 4, 2) SP0; BARR; SCHEDB;

    RDB1(1); RDA1(1);
    MF(WLG12, MM16(a0, b0, 0, 0))
    MF(WLG8,  MM16(a0, b1, 0, 2))
    MF(WLG0,  MM16(a1, b0, 4, 0))
    SCHEDB; SP1; MM16(a1, b1, 4, 2) SP0;

    // Epilogue. C/D layout: col = lane&15, row = (lane>>4)*4 + reg.
    const int quad  = lane >> 4;
    const int crow0 = bm * BMT + wr * 128 + quad * 4;
    const int ccol0 = bn * BNT + wc * 64 + frow;
#pragma unroll
    for (int mi = 0; mi < 8; ++mi)
#pragma unroll
        for (int ni = 0; ni < 4; ++ni) {
            float* cp = C + (size_t)(crow0 + mi * 16) * O_DIM + (ccol0 + ni * 16);
#pragma unroll
            for (int r = 0; r < 4; ++r)
                cp[(size_t)r * O_DIM] = acc[mi][ni][r];
        }
}

extern "C" void kernel_launch(void* const* d_in, const int* in_sizes, int n_in,
                              void* d_out, int out_size, void* d_ws, size_t ws_size,
                              hipStream_t stream) {
    const float* x  = (const float*)d_in[0];
    const float* w  = (const float*)d_in[1];
    const float* ws = (const float*)d_in[2];
    float* out = (float*)d_out;

    short* xb = (short*)d_ws;                       // 64 MiB bf16 x
    short* wb = xb + (size_t)M_DIM * K_DIM;         // 32 MiB bf16 dequant w

    cvt_x<<<2048, 256, 0, stream>>>(x, xb);
    cvt_w<<<2048, 256, 0, stream>>>(w, ws, wb);

    gemm_bt<<<(M_DIM / BMT) * (O_DIM / BNT), 512, 0, stream>>>(xb, wb, out);
}